// Round 8
// baseline (125.247 us; speedup 1.0000x reference)
//
#include <hip/hip_runtime.h>
#include <hip/hip_bf16.h>

// B=4, C=256, H=W=64, O=256, K=3, PAD=2, DIL=2; offset conv: 18ch 3x3 p1 d1.
// R16 == R15 resubmitted (R15 bench died to "container failed twice" infra
// error; kernel audited: uniform barriers, LDS in-bounds (max 8155/8151/
// 7932 < 8160), 158.5KB < 160KB, launch_bounds(1024,4) consistent).
// R15: occupancy-within-structure. R14 (transpose b128 layout) won 30us via
// LDS-instr reduction; still latency-bound (Occ 18.5% < 25% cap, no pipe
// >25%). All-resident x => 1 block/CU, but block can be 1024 thr = 16 waves
// = 4 waves/SIMD (2x latency hiding):
//   - pass 2: 16 waves x 16 o's each (A-traffic/CU unchanged, 8 MFMA/wave
//     per chunk); sampling stays on waves 0..7.
//   - pass 1: R10-verified (mtA,ntA,ktA) 16-wave split + LDS kt-reduction
//     (s_red aliased in colf[0], s_off in colf[1]).
//   - s_xp row stride 16->17, grp stride 960->1020 u32 (== 28 mod 32):
//     conv-gather quad planes + sampler rows decorrelate in banks.
// All verified math (MFMA frag layouts, sampling, phase-B) unchanged.

typedef __attribute__((ext_vector_type(8))) short short8;
typedef __attribute__((ext_vector_type(4))) float floatx4;

__device__ inline unsigned short f2bf(float f) {  // RNE fp32 -> bf16 bits
  unsigned int u = __float_as_uint(f);
  u += 0x7fff + ((u >> 16) & 1);
  return (unsigned short)(u >> 16);
}
__device__ inline float bflo(unsigned int u) { return __uint_as_float(u << 16); }
__device__ inline float bfhi(unsigned int u) {
  return __uint_as_float(u & 0xffff0000u);
}
// packed fp32x2 -> bf16x2 (RNE); compiler emits v_cvt_pk_bf16_f32
__device__ __forceinline__ unsigned int pkbf(float a, float b) {
  __hip_bfloat162 h = __float22bfloat162_rn(make_float2(a, b));
  unsigned int u;
  __builtin_memcpy(&u, &h, 4);
  return u;
}
__device__ __forceinline__ short8 pack4(unsigned int u0, unsigned int u1,
                                        unsigned int u2, unsigned int u3) {
  short8 b;
  b[0] = (short)(u0 & 0xffff);
  b[1] = (short)(u0 >> 16);
  b[2] = (short)(u1 & 0xffff);
  b[3] = (short)(u1 >> 16);
  b[4] = (short)(u2 & 0xffff);
  b[5] = (short)(u2 >> 16);
  b[6] = (short)(u3 & 0xffff);
  b[7] = (short)(u3 >> 16);
  return b;
}

// ---------------------------------------------------------------------------
// prep (coalesced, R11-verified). Thread g<8192: (o=g>>5, c8=g&31) reads 72
// contiguous floats dw[o][c8*8..+7][0..8] as 18x float4, emits 9 short8
// frags: wfrag[ci=cb*9+n][mt=o>>4][kt=(c8>>2)&1][lane=(c8&3)*16+(o&15)][j].
// g in [8192,9216): same for wfragA (o<18 real, else zeros). Then all
// threads grid-stride copy dw -> out tail (replaces memcpy dispatch).
// ---------------------------------------------------------------------------
__global__ __launch_bounds__(256) void prep_kernel(
    const float* __restrict__ dw, const float* __restrict__ ow,
    unsigned short* __restrict__ wfrag, unsigned short* __restrict__ wfragA,
    float* __restrict__ dwcopy) {
  int g = blockIdx.x * 256 + threadIdx.x;
  if (g < 8192) {
    int o = g >> 5, c8 = g & 31;
    int cb = c8 >> 3, kt = (c8 >> 2) & 1, lh = c8 & 3;
    int mt = o >> 4, lane = lh * 16 + (o & 15);
    float f[72];
    const float4* src = (const float4*)(dw + o * 2304 + c8 * 72);
#pragma unroll
    for (int q = 0; q < 18; ++q) {
      float4 t4 = src[q];
      f[4 * q] = t4.x;
      f[4 * q + 1] = t4.y;
      f[4 * q + 2] = t4.z;
      f[4 * q + 3] = t4.w;
    }
#pragma unroll
    for (int n = 0; n < 9; ++n) {
      int ci = cb * 9 + n;
      short8 v;
#pragma unroll
      for (int j = 0; j < 8; ++j) v[j] = (short)f2bf(f[j * 9 + n]);
      *((short8*)wfrag + ((ci * 16 + mt) * 2 + kt) * 64 + lane) = v;
    }
  } else if (g < 9216) {
    int t = g - 8192;
    int o = t >> 5, c8 = t & 31;
    int cb = c8 >> 3, kt = (c8 >> 2) & 1, lh = c8 & 3;
    int mt = o >> 4, lane = lh * 16 + (o & 15);
    float f[72];
    if (o < 18) {
      const float4* src = (const float4*)(ow + o * 2304 + c8 * 72);
#pragma unroll
      for (int q = 0; q < 18; ++q) {
        float4 t4 = src[q];
        f[4 * q] = t4.x;
        f[4 * q + 1] = t4.y;
        f[4 * q + 2] = t4.z;
        f[4 * q + 3] = t4.w;
      }
    } else {
#pragma unroll
      for (int q = 0; q < 72; ++q) f[q] = 0.f;
    }
#pragma unroll
    for (int n = 0; n < 9; ++n) {
      int ci = cb * 9 + n;
      short8 v;
#pragma unroll
      for (int j = 0; j < 8; ++j) v[j] = (short)f2bf(f[j * 9 + n]);
      *((short8*)wfragA + ((ci * 2 + kt) * 2 + mt) * 64 + lane) = v;
    }
  }
  // coalesced deform_w copy to out tail
  const float4* s = (const float4*)dw;
  float4* d = (float4*)dwcopy;
  for (int i = g; i < 147456; i += 32768) d[i] = s[i];
}

// s_xp geometry: [cb][grp=8][pos = ry*17 + rx (15 rows, 16 stored cols, 15
// valid)][q=4] u32; grp stride 1020 u32 (== 28 mod 32: bank-decorrelated).
#define GRPS 1020
#define ROWS 17

// ---------------------------------------------------------------------------
// stage one cb tile (transposed layout). Thread per (grp,pos): 8 coalesced
// global loads -> 4 cvt_pk -> 1 ds_write_b128.
// ---------------------------------------------------------------------------
__device__ __forceinline__ void stage_tile(unsigned int* __restrict__ dst,
                                           const float* __restrict__ xcb,
                                           int h0, int w0, int tid) {
  for (int e = tid; e < 1920; e += 1024) {
    int grp = e / 240, pos = e - grp * 240;
    int ry = pos >> 4, rx = pos & 15;
    int gy = h0 - 3 + ry, gx = w0 - 3 + rx;
    bool ok = (rx < 15 && gy >= 0 && gy < 64 && gx >= 0 && gx < 64);
    unsigned int q0 = 0, q1 = 0, q2 = 0, q3 = 0;
    if (ok) {
      const float* p0 = xcb + (size_t)(grp * 8) * 4096 + (gy * 64 + gx);
      q0 = pkbf(p0[0], p0[4096]);
      q1 = pkbf(p0[8192], p0[12288]);
      q2 = pkbf(p0[16384], p0[20480]);
      q3 = pkbf(p0[24576], p0[28672]);
    }
    *(uint4*)&dst[grp * GRPS + (ry * ROWS + rx) * 4] =
        make_uint4(q0, q1, q2, q3);
  }
}

// ---------------------------------------------------------------------------
// Deform sampler for one chunk (cb, n), 8x8 px tile (R8-verified colf
// layout): thread = (oct = wave 0..7, px = lane). oct covers planes oct*4+q
// (8 channels). 4 corner ds_read_b128 -> bilinear -> 4 cvt_pk -> one b128
// write into colf. colf [nt=4][kt=2][lane=64][j=8]: lane = (px&15)|(qk<<4),
// nt=px>>4, kt=oct>>2, qk=oct&3, j=2q+h (channel cl = oct*8 + 2q + h).
// ---------------------------------------------------------------------------
__device__ __forceinline__ void sample_chunk(
    const unsigned int* __restrict__ xpcb, int n,
    unsigned short* __restrict__ colf, int oct, int px,
    const float (*sw4)[64][4], const int (*scoff)[64]) {
  float4 wq = *(const float4*)&sw4[n][px][0];
  const unsigned int* bp = xpcb + oct * GRPS + scoff[n][px];
  uint4 A = *(const uint4*)(bp);                 // (y0,x0)
  uint4 Bv = *(const uint4*)(bp + 4);            // (y0,x0+1)
  uint4 Cv = *(const uint4*)(bp + 4 * ROWS);     // (y0+1,x0)
  uint4 Dv = *(const uint4*)(bp + 4 * ROWS + 4); // (y0+1,x0+1)
  unsigned int w[4];
#define BILIN(qi, ua, ub, uc, ud)                                       \
  {                                                                     \
    float lo = wq.x * bflo(ua) + wq.y * bflo(ub) + wq.z * bflo(uc) +    \
               wq.w * bflo(ud);                                         \
    float hi = wq.x * bfhi(ua) + wq.y * bfhi(ub) + wq.z * bfhi(uc) +    \
               wq.w * bfhi(ud);                                         \
    w[qi] = pkbf(lo, hi);                                               \
  }
  BILIN(0, A.x, Bv.x, Cv.x, Dv.x)
  BILIN(1, A.y, Bv.y, Cv.y, Dv.y)
  BILIN(2, A.z, Bv.z, Cv.z, Dv.z)
  BILIN(3, A.w, Bv.w, Cv.w, Dv.w)
#undef BILIN
  uint4 vv = make_uint4(w[0], w[1], w[2], w[3]);
  int nt = px >> 4, kt = oct >> 2, qk = oct & 3;
  *(uint4*)&colf[((nt * 2 + kt) * 64 + ((px & 15) | (qk << 4))) * 8] = vv;
}

// ---------------------------------------------------------------------------
// Fused: stage-once x (4 resident cb tiles, staggered) + offset conv +
// sample + GEMM. 8x8 px tile, 256 o, 1024 thr (16 waves -> 4 waves/SIMD),
// 256 blocks = 1/CU.
// LDS: s_xp 4x8160x4 = 130560 + colf 16384 + w4 9216 + coff 2304 = 158464.
// ---------------------------------------------------------------------------
__global__ __launch_bounds__(1024, 4) void deform_kernel(
    const float* __restrict__ x, const float* __restrict__ obias,
    const unsigned short* __restrict__ wfragA,
    const unsigned short* __restrict__ wfrag, const float* __restrict__ bias,
    float* __restrict__ out) {
  int tid = threadIdx.x;
  int b = blockIdx.y, tile = blockIdx.x;
  int h0 = (tile >> 3) * 8, w0 = (tile & 7) * 8;
  int lane = tid & 63, wv = tid >> 6;  // wv 0..15

  __shared__ __align__(16) unsigned int s_xp[4][8160];
  __shared__ __align__(16) unsigned short s_colf[2][4096];
  __shared__ __align__(16) float s_w4[9][64][4];
  __shared__ int s_coff[9][64];

  const float* xb = x + (size_t)b * 256 * 4096;

  // ---- pass 1: staggered stage + offset conv (18(pad32)x64 output) ----
  // 16 waves = (mtA = wv>>3, ntA = (wv>>1)&3, ktA = wv&1); 9 MFMA per cb;
  // kt halves reduced via LDS afterward (R10-verified pattern).
  int mtA = wv >> 3, ntA = (wv >> 1) & 3, ktA = wv & 1;
  int kqA = lane >> 4;
  int pA = ntA * 16 + (lane & 15);
  int pyA = pA >> 3, pxA = pA & 7;
  const short8* wAg = (const short8*)wfragA;
  floatx4 aoff = (floatx4)(0.f);

  stage_tile(s_xp[0], xb, h0, w0, tid);
  __syncthreads();

  for (int cb = 0; cb < 4; ++cb) {
    const unsigned int* xp = s_xp[cb];
#pragma unroll
    for (int t = 0; t < 9; ++t) {
      int ty = t / 3, tx = t - ty * 3;
      int ci = cb * 9 + t;
      short8 aA = wAg[((ci * 2 + ktA) * 2 + mtA) * 64 + lane];
      int po = (pyA + ty + 2) * ROWS + (pxA + tx + 2);
      uint4 X = *(const uint4*)(xp + (ktA * 4 + kqA) * GRPS + po * 4);
      short8 bfr = pack4(X.x, X.y, X.z, X.w);
      aoff = __builtin_amdgcn_mfma_f32_16x16x32_bf16(aA, bfr, aoff, 0, 0, 0);
    }
    // stage cb+1 (overlaps other waves' conv)
    if (cb < 3) stage_tile(s_xp[cb + 1], xb + (cb + 1) * 262144, h0, w0, tid);
    __syncthreads();
  }

  // kt-half reduction through LDS: s_red aliased into colf[0] (8KB),
  // s_off into colf[1]; both dead until chunk sampling (after phase B).
  {
    float* s_red = (float*)&s_colf[0][0];  // [8 combos][64 lanes][4]
    if (ktA == 1) {
#pragma unroll
      for (int r = 0; r < 4; ++r)
        s_red[((mtA * 4 + ntA) * 64 + lane) * 4 + r] = aoff[r];
    }
  }
  __syncthreads();
  {
    const float* s_red = (const float*)&s_colf[0][0];
    float* s_off = (float*)&s_colf[1][0];  // [o=18][px=64]
    if (ktA == 0) {
#pragma unroll
      for (int r = 0; r < 4; ++r) {
        float v = aoff[r] + s_red[((mtA * 4 + ntA) * 64 + lane) * 4 + r];
        int o = mtA * 16 + kqA * 4 + r;  // C/D row = quad*4+r (R6-verified)
        if (o < 18) s_off[o * 64 + pA] = v;
      }
    }
  }
  __syncthreads();

  // ---- phase B (R6-verified math): bias + clip fused ----
  if (tid < 576) {
    const float* s_off = (const float*)&s_colf[1][0];
    int n = tid >> 6, pe = tid & 63;
    int hy = h0 + (pe >> 3), wx = w0 + (pe & 7);
    float dy = s_off[(2 * n) * 64 + pe] + obias[2 * n];
    float dx = s_off[(2 * n + 1) * 64 + pe] + obias[2 * n + 1];
    dy = fminf(fmaxf(dy, -1.f), 1.f);
    dx = fminf(fmaxf(dx, -1.f), 1.f);
    float fy = dy + (float)(hy - 2 + (n / 3) * 2);
    float fx = dx + (float)(wx - 2 + (n % 3) * 2);
    float y0f = floorf(fy), x0f = floorf(fx);
    float wy1 = fy - y0f, wx1 = fx - x0f;
    float wy0 = 1.f - wy1, wx0 = 1.f - wx1;
    // premultiplied by 4: u32 index of q0 at (y0,x0) within a grp
    s_coff[n][pe] =
        (((int)y0f - (h0 - 3)) * ROWS + ((int)x0f - (w0 - 3))) * 4;
    s_w4[n][pe][0] = wy0 * wx0;
    s_w4[n][pe][1] = wy0 * wx1;
    s_w4[n][pe][2] = wy1 * wx0;
    s_w4[n][pe][3] = wy1 * wx1;
  }
  __syncthreads();

  // ---- pass 2: sample + GEMM. 16-way M-split: wave wv owns o in
  // [wv*16, wv*16+16), full N=64 (tn 0..3); 8 MFMA/chunk/wave. Sampling on
  // waves 0..7 only (oct = wv). A-frag prefetch 1 chunk ahead. ----

  // prologue: sample chunk 0 -> colf[0]; prefetch areg for ci=0 (mt = wv)
  if (wv < 8) sample_chunk(s_xp[0], 0, s_colf[0], wv, lane, s_w4, s_coff);
  short8 areg[2];
  {
    const short8* wg = (const short8*)wfrag;
#pragma unroll
    for (int kt = 0; kt < 2; ++kt)
      areg[kt] = wg[((0 * 16 + wv) * 2 + kt) * 64 + lane];
  }
  __syncthreads();

  floatx4 acc[4];
#pragma unroll
  for (int j = 0; j < 4; ++j) acc[j] = (floatx4)(0.f);

  for (int cb = 0; cb < 4; ++cb) {
    for (int n = 0; n < 9; ++n) {
      int ci = cb * 9 + n;

      // prefetch A-frags for chunk ci+1 (consumed next iter; hides L2)
      short8 anx[2];
      if (ci + 1 < 36) {
        const short8* wg = (const short8*)wfrag;
#pragma unroll
        for (int kt = 0; kt < 2; ++kt)
          anx[kt] = wg[(((ci + 1) * 16 + wv) * 2 + kt) * 64 + lane];
      }

      // sample chunk ci+1 -> colf[(ci+1)&1] (x tiles all resident)
      if (ci + 1 < 36 && wv < 8) {
        int nn = n + 1, cbn = cb;
        if (nn == 9) {
          nn = 0;
          cbn = cb + 1;
        }
        sample_chunk(s_xp[cbn], nn, s_colf[(ci + 1) & 1], wv, lane, s_w4,
                     s_coff);
      }

      // MFMA chunk ci from colf[ci&1]
      const unsigned short* cf = s_colf[ci & 1];
#pragma unroll
      for (int kt = 0; kt < 2; ++kt) {
        short8 bfr[4];
#pragma unroll
        for (int tn = 0; tn < 4; ++tn)
          bfr[tn] = *(const short8*)&cf[((tn * 2 + kt) * 64 + lane) * 8];
#pragma unroll
        for (int tn = 0; tn < 4; ++tn)
          acc[tn] = __builtin_amdgcn_mfma_f32_16x16x32_bf16(areg[kt], bfr[tn],
                                                            acc[tn], 0, 0, 0);
      }
      __syncthreads();

#pragma unroll
      for (int kt = 0; kt < 2; ++kt) areg[kt] = anx[kt];
    }
  }

  // epilogue (R5-verified C/D layout): col=lane&15, row=quad*4+r
  int quad = lane >> 4, col = lane & 15;
#pragma unroll
  for (int tn = 0; tn < 4; ++tn) {
    int pxo = tn * 16 + col;
    int h = h0 + (pxo >> 3), w = w0 + (pxo & 7);
#pragma unroll
    for (int r = 0; r < 4; ++r) {
      int o = wv * 16 + quad * 4 + r;
      out[(((size_t)b * 256 + o) * 64 + h) * 64 + w] = acc[tn][r] + bias[o];
    }
  }
}

extern "C" void kernel_launch(void* const* d_in, const int* in_sizes, int n_in,
                              void* d_out, int out_size, void* d_ws,
                              size_t ws_size, hipStream_t stream) {
  (void)in_sizes; (void)n_in; (void)out_size; (void)ws_size;
  const float* x        = (const float*)d_in[0];  // (4,256,64,64)
  const float* offset_w = (const float*)d_in[1];  // (18,256,3,3)
  const float* offset_b = (const float*)d_in[2];  // (18,)
  const float* deform_w = (const float*)d_in[3];  // (256,256,3,3)
  const float* deform_b = (const float*)d_in[4];  // (256,)
  float* out = (float*)d_out;

  unsigned short* wfrag = (unsigned short*)d_ws;  // 589824 bf16
  unsigned short* wfragA = wfrag + 589824;        // 73728 bf16

  prep_kernel<<<128, 256, 0, stream>>>(deform_w, offset_w, wfrag, wfragA,
                                       out + 4194304);
  deform_kernel<<<dim3(64, 4), 1024, 0, stream>>>(x, offset_b, wfragA, wfrag,
                                                  deform_b, out);
}